// Round 3
// baseline (378.820 us; speedup 1.0000x reference)
//
#include <hip/hip_runtime.h>

// Problem constants (from reference)
#define GG 76
#define AA 3
#define S1C (GG*GG*AA)          // 17328
#define SDIM 22743              // 3*(76^2+38^2+19^2)
#define CCH 85
#define BB 16
#define NROWS (BB*SDIM)         // 363888 rows of 85 floats
#define NELEM (NROWS*CCH)       // 30930480 elements
#define NV (NELEM/4)            // 7732620 float4s (divides exactly)

// ---------------------------------------------------------------------------
// Kernel 1: per-row objectness mask weight (byte per row).
// mask[r] = 0 for s >= S1; else 1 if (a==argmax_a iou) or iou<=0.7 else 0.
// Anchors and gt boxes are both origin-centered -> iou reduces exactly.
// ---------------------------------------------------------------------------
__global__ __launch_bounds__(256) void mask_kernel(const float* __restrict__ t,
                                                   unsigned char* __restrict__ maskb) {
    unsigned r = blockIdx.x * blockDim.x + threadIdx.x;
    if (r >= (unsigned)NROWS) return;
    unsigned b = r / (unsigned)SDIM;
    unsigned s = r - b * (unsigned)SDIM;
    if (s >= (unsigned)S1C) { maskb[r] = 0; return; }
    unsigned g = s / 3u;
    unsigned a = s - g * 3u;
    unsigned rbase = b * (unsigned)SDIM + g * 3u;
    const float AW[3] = {10.f, 16.f, 33.f};
    const float AH[3] = {13.f, 30.f, 23.f};
    float iou[3];
#pragma unroll
    for (int k = 0; k < 3; ++k) {
        float gw = t[(size_t)(rbase + k) * CCH + 2];
        float gh = t[(size_t)(rbase + k) * CCH + 3];
        float aw = AW[k], ah = AH[k];
        // boxes centered at origin: overlap = min of half-extents both sides
        float iw = fmaxf(fminf(aw * 0.5f, gw * 0.5f) - fmaxf(-aw * 0.5f, -gw * 0.5f), 0.f);
        float ih = fmaxf(fminf(ah * 0.5f, gh * 0.5f) - fmaxf(-ah * 0.5f, -gh * 0.5f), 0.f);
        float inter = iw * ih;
        float a1 = aw * ah;
        float a2 = gw * gh;
        iou[k] = inter / (a1 + a2 - inter + 1e-16f);
    }
    int best = 0;                         // jnp.argmax: first max wins
    if (iou[1] > iou[0]) best = 1;
    if (iou[2] > iou[best]) best = 2;
    maskb[r] = ((int)a == best) ? 1 : (iou[a] <= 0.7f ? 1 : 0);
}

// ---------------------------------------------------------------------------
// Kernel 2: fused BCE + reductions. Flat float4 grid-stride over B*S*C.
// sums[0]=xy, sums[1]=wh, sums[2]=cls, sums[3]=obj, sums[4]=count(m)
// ---------------------------------------------------------------------------
__global__ __launch_bounds__(256) void loss_kernel(const float* __restrict__ x,
                                                   const float* __restrict__ t,
                                                   const unsigned char* __restrict__ maskb,
                                                   double* __restrict__ sums) {
    float s_xy = 0.f, s_wh = 0.f, s_cls = 0.f, s_obj = 0.f, s_m = 0.f;
    const float4* x4 = (const float4*)x;
    const float4* t4 = (const float4*)t;
    unsigned stride = gridDim.x * blockDim.x;
    for (unsigned v = blockIdx.x * blockDim.x + threadIdx.x; v < (unsigned)NV; v += stride) {
        float4 xv = x4[v];
        float4 tv = t4[v];
        unsigned idx0 = v * 4u;
        unsigned row0 = idx0 / (unsigned)CCH;
        unsigned c0   = idx0 - row0 * (unsigned)CCH;
        float mk0 = (float)maskb[row0];
        float mk1 = 0.f, m1 = 0.f, m0 = 0.f;
        if (c0 <= 4u)                               // window touches c<5 of row0
            m0 = (t[(size_t)row0 * CCH + 4] > 0.f) ? 1.f : 0.f;
        if (c0 >= (unsigned)(CCH - 3)) {            // window wraps into row0+1
            mk1 = (float)maskb[row0 + 1u];
            m1 = (t[(size_t)(row0 + 1u) * CCH + 4] > 0.f) ? 1.f : 0.f;
        }
        float xe[4] = {xv.x, xv.y, xv.z, xv.w};
        float te[4] = {tv.x, tv.y, tv.z, tv.w};
#pragma unroll
        for (int j = 0; j < 4; ++j) {
            unsigned c = c0 + (unsigned)j;
            float mk = mk0, mrow = m0;
            if (c >= (unsigned)CCH) { c -= (unsigned)CCH; mk = mk1; mrow = m1; }
            float p = xe[j], tt = te[j];
            float lg  = fmaxf(logf(p), -100.f);
            float lg1 = fmaxf(logf(1.f - p), -100.f);
            float bce = -(tt * lg + (1.f - tt) * lg1);
            s_obj += bce * mk;                      // mk==0 for s>=S1 or ignored
            if (c < 5u) {
                float wb = bce * mrow;
                if (c < 2u)      s_xy  += wb;
                else if (c < 4u) s_wh  += wb;
                else             { s_cls += wb; s_m += mrow; } // once per row
            }
        }
    }
    // wave(64) shuffle reduce -> LDS across 4 waves -> 5 double atomics
    float vals[5] = {s_xy, s_wh, s_cls, s_obj, s_m};
#pragma unroll
    for (int k = 0; k < 5; ++k) {
        float a = vals[k];
        for (int off = 32; off > 0; off >>= 1) a += __shfl_down(a, off, 64);
        vals[k] = a;
    }
    __shared__ float red[4][5];
    int lane = threadIdx.x & 63, wid = threadIdx.x >> 6;
    if (lane == 0) {
#pragma unroll
        for (int k = 0; k < 5; ++k) red[wid][k] = vals[k];
    }
    __syncthreads();
    if (threadIdx.x == 0) {
#pragma unroll
        for (int k = 0; k < 5; ++k) {
            double tot = (double)red[0][k] + (double)red[1][k] +
                         (double)red[2][k] + (double)red[3][k];
            atomicAdd(&sums[k], tot);
        }
    }
}

// ---------------------------------------------------------------------------
// Kernel 3: finalize scalar loss.
// ---------------------------------------------------------------------------
__global__ void finalize_kernel(const double* __restrict__ sums,
                                float* __restrict__ out) {
    double cnt = fmax(sums[4], 1.0);
    double obj_denom = (double)BB * (double)S1C * (double)CCH;  // 23,566,080
    double loss = sums[0] / (2.0 * cnt) + sums[1] / (2.0 * cnt) +
                  sums[2] / cnt + sums[3] / obj_denom;
    out[0] = (float)loss;
}

extern "C" void kernel_launch(void* const* d_in, const int* in_sizes, int n_in,
                              void* d_out, int out_size, void* d_ws, size_t ws_size,
                              hipStream_t stream) {
    (void)in_sizes; (void)n_in; (void)out_size; (void)ws_size;
    const float* x = (const float*)d_in[0];
    const float* t = (const float*)d_in[1];
    double* sums        = (double*)d_ws;                    // 5 doubles (64B slot)
    unsigned char* maskb = (unsigned char*)d_ws + 64;       // NROWS bytes (~364 KB)

    hipMemsetAsync(d_ws, 0, 64, stream);                    // zero accumulators

    mask_kernel<<<(NROWS + 255) / 256, 256, 0, stream>>>(t, maskb);
    loss_kernel<<<2048, 256, 0, stream>>>(x, t, maskb, sums);
    finalize_kernel<<<1, 1, 0, stream>>>(sums, (float*)d_out);
}

// Round 8
// 376.485 us; speedup vs baseline: 1.0062x; 1.0062x over previous
//
#include <hip/hip_runtime.h>

// Problem constants (from reference)
#define GG 76
#define AA 3
#define S1C (GG*GG*AA)          // 17328
#define SDIM 22743              // 3*(76^2+38^2+19^2)
#define CCH 85
#define BB 16
#define NROWS (BB*SDIM)         // 363888 rows of 85 floats
#define NELEM (NROWS*CCH)       // 30930480 elements
#define NV (NELEM/4)            // 7732620 float4s (divides exactly)
#define NCELL (BB*GG*GG)        // 92416 (b,g) cells

// fast ln: v_log_f32 (log2) * ln2. Inputs here are in (1e-4, 1-1e-4): safe.
__device__ __forceinline__ float fast_ln(float v) {
    return __logf(v);
}

// ---------------------------------------------------------------------------
// Kernel 1: per-(b,g) mask: 3 bytes (one per anchor a).
// mask=1 iff a==argmax_a(iou) or iou<=0.7. Rows s>=S1 pre-zeroed by memset.
// Origin-centered boxes: iw==min(aw,gw), ih==min(ah,gh) exactly in fp32.
// ---------------------------------------------------------------------------
__global__ __launch_bounds__(256) void mask_kernel(const float* __restrict__ t,
                                                   unsigned char* __restrict__ maskb) {
    unsigned cell = blockIdx.x * blockDim.x + threadIdx.x;
    if (cell >= (unsigned)NCELL) return;
    unsigned b = cell / (unsigned)(GG*GG);
    unsigned g = cell - b * (unsigned)(GG*GG);
    unsigned r0 = b * (unsigned)SDIM + g * 3u;
    const float AW[3] = {10.f, 16.f, 33.f};
    const float AH[3] = {13.f, 30.f, 23.f};
    float iou[3];
#pragma unroll
    for (int k = 0; k < 3; ++k) {
        float gw = t[(size_t)(r0 + k) * CCH + 2];
        float gh = t[(size_t)(r0 + k) * CCH + 3];
        float inter = fminf(AW[k], gw) * fminf(AH[k], gh);
        iou[k] = inter / (AW[k] * AH[k] + gw * gh - inter + 1e-16f);
    }
    int best = 0;                        // jnp.argmax: first max wins
    if (iou[1] > iou[0]) best = 1;
    if (iou[2] > iou[best]) best = 2;
#pragma unroll
    for (int k = 0; k < 3; ++k)
        maskb[r0 + k] = (k == best) ? 1 : (iou[k] <= 0.7f ? 1 : 0);
}

// ---------------------------------------------------------------------------
// Kernel 2: fused BCE + reductions, float4 stream, unroll x4 for MLP/ILP.
// acc[0]=xy, acc[1]=wh, acc[2]=cls, acc[3]=obj, acc[4]=count(m)
// ---------------------------------------------------------------------------
__device__ __forceinline__ void process_window(unsigned v,
                                               float4 xv, float4 tv,
                                               const float* __restrict__ t,
                                               const unsigned char* __restrict__ maskb,
                                               float acc[5]) {
    unsigned idx0 = v * 4u;
    unsigned row0 = idx0 / (unsigned)CCH;            // magic-mul division
    unsigned c0   = idx0 - row0 * (unsigned)CCH;
    float te[4] = {tv.x, tv.y, tv.z, tv.w};
    float xe[4] = {xv.x, xv.y, xv.z, xv.w};
    float mk0 = (float)maskb[row0];
    float mk1 = 0.f, m0 = 0.f, m1 = 0.f;
    if (c0 <= 4u) {                                  // window touches c<5 of row0
        // t[row0,4]: inside this window when 1<=c0<=4, else one scalar load
        float t4v = (c0 == 0u) ? t[(size_t)row0 * CCH + 4]
                               : te[4u - c0];
        m0 = (t4v > 0.f) ? 1.f : 0.f;
    }
    if (c0 >= (unsigned)(CCH - 3)) {                 // wraps into row0+1 (c'<4 only)
        mk1 = (float)maskb[row0 + 1u];
        m1  = (t[(size_t)(row0 + 1u) * CCH + 4] > 0.f) ? 1.f : 0.f;
    }
#pragma unroll
    for (int j = 0; j < 4; ++j) {
        unsigned c = c0 + (unsigned)j;
        float mk = mk0, mrow = m0;
        if (c >= (unsigned)CCH) { c -= (unsigned)CCH; mk = mk1; mrow = m1; }
        float p = xe[j], tt = te[j];
        float lg  = fmaxf(fast_ln(p), -100.f);
        float lg1 = fmaxf(fast_ln(1.f - p), -100.f);
        float bce = -(tt * lg + (1.f - tt) * lg1);
        acc[3] += bce * mk;                          // mk==0 for s>=S1 or ignored
        if (c < 5u) {
            float wb = bce * mrow;
            if (c < 2u)      acc[0] += wb;
            else if (c < 4u) acc[1] += wb;
            else             { acc[2] += wb; acc[4] += mrow; }  // once per row
        }
    }
}

__global__ __launch_bounds__(256) void loss_kernel(const float* __restrict__ x,
                                                   const float* __restrict__ t,
                                                   const unsigned char* __restrict__ maskb,
                                                   double* __restrict__ sums) {
    float acc[5] = {0.f, 0.f, 0.f, 0.f, 0.f};
    const float4* x4 = (const float4*)x;
    const float4* t4 = (const float4*)t;
    const unsigned S = gridDim.x * blockDim.x;
    unsigned v = blockIdx.x * blockDim.x + threadIdx.x;
    // main loop: 4 independent windows in flight per wave
    for (; v + 3u * S < (unsigned)NV; v += 4u * S) {
        unsigned vv0 = v, vv1 = v + S, vv2 = v + 2u * S, vv3 = v + 3u * S;
        float4 xa = x4[vv0], ta = t4[vv0];
        float4 xb = x4[vv1], tb = t4[vv1];
        float4 xc = x4[vv2], tc = t4[vv2];
        float4 xd = x4[vv3], td = t4[vv3];
        process_window(vv0, xa, ta, t, maskb, acc);
        process_window(vv1, xb, tb, t, maskb, acc);
        process_window(vv2, xc, tc, t, maskb, acc);
        process_window(vv3, xd, td, t, maskb, acc);
    }
    for (; v < (unsigned)NV; v += S)
        process_window(v, x4[v], t4[v], t, maskb, acc);

    // wave(64) shuffle reduce -> LDS across 4 waves -> 5 double atomics
#pragma unroll
    for (int k = 0; k < 5; ++k) {
        float a = acc[k];
        for (int off = 32; off > 0; off >>= 1) a += __shfl_down(a, off, 64);
        acc[k] = a;
    }
    __shared__ float red[4][5];
    int lane = threadIdx.x & 63, wid = threadIdx.x >> 6;
    if (lane == 0) {
#pragma unroll
        for (int k = 0; k < 5; ++k) red[wid][k] = acc[k];
    }
    __syncthreads();
    if (threadIdx.x == 0) {
#pragma unroll
        for (int k = 0; k < 5; ++k) {
            double tot = (double)red[0][k] + (double)red[1][k] +
                         (double)red[2][k] + (double)red[3][k];
            atomicAdd(&sums[k], tot);
        }
    }
}

// ---------------------------------------------------------------------------
// Kernel 3: finalize scalar loss.
// ---------------------------------------------------------------------------
__global__ void finalize_kernel(const double* __restrict__ sums,
                                float* __restrict__ out) {
    double cnt = fmax(sums[4], 1.0);
    double obj_denom = (double)BB * (double)S1C * (double)CCH;  // 23,566,080
    double loss = sums[0] / (2.0 * cnt) + sums[1] / (2.0 * cnt) +
                  sums[2] / cnt + sums[3] / obj_denom;
    out[0] = (float)loss;
}

extern "C" void kernel_launch(void* const* d_in, const int* in_sizes, int n_in,
                              void* d_out, int out_size, void* d_ws, size_t ws_size,
                              hipStream_t stream) {
    (void)in_sizes; (void)n_in; (void)out_size; (void)ws_size;
    const float* x = (const float*)d_in[0];
    const float* t = (const float*)d_in[1];
    double* sums         = (double*)d_ws;               // 5 doubles (64B slot)
    unsigned char* maskb = (unsigned char*)d_ws + 64;   // NROWS bytes (~364 KB)

    // zero accumulators + maskb (covers s>=S1 rows) in one async memset
    hipMemsetAsync(d_ws, 0, 64 + NROWS, stream);

    mask_kernel<<<(NCELL + 255) / 256, 256, 0, stream>>>(t, maskb);
    loss_kernel<<<2048, 256, 0, stream>>>(x, t, maskb, sums);
    finalize_kernel<<<1, 1, 0, stream>>>(sums, (float*)d_out);
}